// Round 10
// baseline (1359.444 us; speedup 1.0000x reference)
//
#include <hip/hip_runtime.h>
#include <hip/hip_bf16.h>
#include <math.h>

typedef __attribute__((ext_vector_type(8))) short short8;   // 8 bf16 (4 VGPRs)
typedef __attribute__((ext_vector_type(4))) float f32x4;    // MFMA 16x16 acc
typedef __attribute__((ext_vector_type(4))) unsigned uint4v;
typedef __attribute__((ext_vector_type(4))) unsigned short ushort4v;

static __device__ __forceinline__ short f2b(float f){
  union { float f; unsigned u; } v; v.f = f;
  unsigned r = v.u + 0x7fffu + ((v.u >> 16) & 1u);   // RNE
  return (short)(r >> 16);
}
static __device__ __forceinline__ unsigned f2b2(float x, float y){
  union { __hip_bfloat162 h; unsigned u; } cv;
  cv.h = __float22bfloat162_rn(make_float2(x, y));
  return cv.u;
}
static __device__ __forceinline__ float blo(unsigned u){ return __uint_as_float(u << 16); }
static __device__ __forceinline__ float bhi(unsigned u){ return __uint_as_float(u & 0xffff0000u); }

// ---- workspace layout (float offsets; all multiples of 4 -> 16B aligned) ----
constexpr size_t OFF_CUR   = 0;                         // bf16 [4][16384][64] NHWC (8MB of 16MB slot)
constexpr size_t OFF_BAR   = OFF_CUR  + 2097152;        // global barrier counter (in dead CUR tail)
constexpr size_t OFF_DC    = OFF_CUR  + 4194304;        // f32 4*16384*64 NHWC
constexpr size_t OFF_T0    = OFF_DC   + 4194304;        // fuse outputs, CHW [b][o][p], f32
constexpr size_t OFF_T1    = OFF_T0   + 4194304;
constexpr size_t OFF_T2    = OFF_T1   + 1048576;
constexpr size_t OFF_T3    = OFF_T2   + 262144;
constexpr size_t OFF_WSUMT = OFF_T3   + 65536;          // bf16 [4][64][64]   kdim=c
constexpr size_t OFF_DCWT  = OFF_WSUMT + 8192;          // bf16 [4][64][576]  kdim=k*64+c
constexpr size_t OFF_OWT   = OFF_DCWT  + 73728;         // bf16 [4][32][576]  kdim=k*64+c
constexpr size_t OFF_SUMS  = OFF_OWT   + 36864;         // f32 [4][16 slots][256]

constexpr int SM_BYTES = 31744;                         // deform8 footprint
constexpr int GRID = 512;                               // 2 blocks/CU: co-residency w/ 2x margin

// ---- device-scope global barrier (monotonic; bar memset to 0 per run) ----
static __device__ __forceinline__ void gbar(unsigned* bar, int phase){
  __threadfence_system();
  __syncthreads();
  if (threadIdx.x == 0){
    __hip_atomic_fetch_add(bar, 1u, __ATOMIC_RELEASE, __HIP_MEMORY_SCOPE_AGENT);
    const unsigned target = (unsigned)(phase * GRID);
    long spins = 0;
    while (__hip_atomic_load(bar, __ATOMIC_ACQUIRE, __HIP_MEMORY_SCOPE_AGENT) < target){
      __builtin_amdgcn_s_sleep(8);
      if (++spins > 500000000L) break;      // failsafe: fail, don't hang
    }
  }
  __syncthreads();
  __threadfence_system();
}

// ---- phase: prep (grid-strided) + cvt (tiles grid-strided) ----
static __device__ void prep_body(char* sm, const float* __restrict__ dc_w,
                                 const float* __restrict__ off_w,
                                 const float* __restrict__ fuse_w, float* __restrict__ ws,
                                 const float* __restrict__ x, unsigned* __restrict__ cur,
                                 int bid){
  float (*t)[65] = (float(*)[65])sm;              // 16640B
  const int tid = threadIdx.x;
  {
    short* dcwT  = (short*)(ws + OFF_DCWT);
    short* owT   = (short*)(ws + OFF_OWT);
    short* wsumT = (short*)(ws + OFF_WSUMT);
    for (int i = bid*256 + tid; i < 303104; i += GRID*256){
      if (i < 147456){
        int oc = i / 576, r = i % 576, k = r >> 6, c = r & 63;    // oc = l*64+o
        dcwT[i] = f2b(dc_w[(oc*64 + c)*9 + k]);
      } else if (i < 147456 + 73728){
        int tt = i - 147456;
        int lm = tt / 576, l = lm >> 5, m = lm & 31, r = tt % 576, k = r >> 6, c = r & 63;
        owT[tt] = (m < 18) ? f2b(off_w[((l*18 + m)*64 + c)*9 + k]) : (short)0;
      } else if (i < 147456 + 73728 + 16384){
        int tt = i - (147456 + 73728);
        int l = tt / 4096, r = tt % 4096, o = r / 64, c = r % 64;
        float s = 0.f;
        for (int jl = 0; jl <= l; jl++) s += fuse_w[o*256 + jl*64 + c];
        wsumT[tt] = f2b(s);
      } else {
        ws[OFF_SUMS + (i - (147456 + 73728 + 16384))] = 0.f;
      }
    }
  }
  // cvt tiles: b(4) x 256 pixel-groups = 1024 tiles
  for (int vb = bid; vb < 1024; vb += GRID){
    __syncthreads();                              // t[] reuse fence across iterations
    int b = vb >> 8, p0 = (vb & 255) << 6;
    int tx = tid & 63, ty = tid >> 6;
    #pragma unroll
    for (int c = ty; c < 64; c += 4)
      t[c][tx] = x[(((size_t)(b << 6) + c) << 14) + p0 + tx];
    __syncthreads();
    int u = tid & 31, pr = tid >> 5;
    #pragma unroll
    for (int i = 0; i < 8; i++){
      int pp = pr + i*8;
      unsigned v = f2b2(t[2*u][pp], t[2*u + 1][pp]);
      cur[((size_t)(b << 14) + p0 + pp)*32 + u] = v;
    }
  }
}

// ---- phase: deform8 (verbatim R7 body; 8x8 tile / four 4x4 sub-tiles) ----
template<int H, int LVL>
static __device__ void deform8_body(char* sm, int bid,
    const unsigned* __restrict__ cur, const float* __restrict__ ws_all,
    const float* __restrict__ off_bias, const float* __restrict__ dc_bias,
    float* __restrict__ dc, float* __restrict__ sums){
  constexpr int W = H, P = H * W;
  constexpr int PITCHB = 584 * 2;
  constexpr int TPR8 = W/8, TPB8 = P/64;
  short (*valA)[584] = (short(*)[584])sm;                 // 18688B
  char*  patchS = sm + 18688;                             // 9216B
  float4* tapW = (float4*)(sm + 27904);                   // 2304B
  unsigned short (*tapIs)[4] = (unsigned short(*)[4])(sm + 30208);  // 1152B
  float* offsP = (float*)(sm + 8192);                     // aliases valA upper
  const short* owt = (const short*)(ws_all + OFF_OWT) + LVL * 32 * 576;
  const short* dcw = (const short*)(ws_all + OFF_DCWT) + (size_t)LVL * 64 * 576;
  const int tid = threadIdx.x;
  const int wave = tid >> 6, lane = tid & 63;
  const int c0 = lane & 15, quad = lane >> 4, q4 = quad * 4;
  const int b = bid / TPB8;
  const int rr = bid % TPB8;
  const int hrow8 = (rr / TPR8) * 8, wcol8 = (rr % TPR8) * 8;
  const unsigned* curu = cur + (size_t)b * P * 32;
  const int n = wave*16 + c0;
  const float bt2 = dc_bias[LVL*64 + n];
  const int tk = tid % 9, tp = tid / 9;
  float oby = 0.f, obx = 0.f;
  if (tid < 144){
    oby = off_bias[LVL*18 + 2*tk];
    obx = off_bias[LVL*18 + 2*tk + 1];
  }
  const int pl = lane >> 3, cq = lane & 7;
  __syncthreads();                                // LDS reuse fence (vb-loop safe)

  #pragma unroll 1
  for (int t = 0; t < 4; t++){
    const int srow = hrow8 + (t >> 1)*4, scol = wcol8 + (t & 1)*4;
    if (t) __syncthreads();

    // A: stage 8x8 halo patch (margin +-2)
    #pragma unroll
    for (int i = 0; i < 2; i++){
      int pp = wave*16 + i*8 + pl;
      int R = pp >> 3, C = pp & 7;
      int yy = srow - 2 + R, xx = scol - 2 + C;
      bool v = ((unsigned)yy < (unsigned)H) & ((unsigned)xx < (unsigned)W);
      int idx = v ? (yy*W + xx) : 0;
      uint4 d = *(const uint4*)((const char*)curu + (size_t)idx*128 + cq*16);
      if (!v){ d.x = 0; d.y = 0; d.z = 0; d.w = 0; }
      *(uint4*)(patchS + pp*144 + cq*16) = d;
    }
    __syncthreads();

    // B: offset conv
    {
      const int colw = wave & 1, kh = wave >> 1;
      const char* pb = patchS + (((c0 >> 2) + 1)*8 + (c0 & 3) + 1)*144 + quad*16;
      const short* wrow = owt + (colw*16 + c0)*576 + quad*8;
      f32x4 oacc = {0,0,0,0};
      if (kh == 0){
        #pragma unroll
        for (int kb = 0; kb < 9; kb++){
          const int tap = kb >> 1;
          short8 a  = *(const short8*)(pb + ((tap/3)*8 + (tap%3))*144 + (kb&1)*64);
          short8 bf = *(const short8*)&wrow[kb*32];
          oacc = __builtin_amdgcn_mfma_f32_16x16x32_bf16(a, bf, oacc, 0, 0, 0);
        }
      } else {
        #pragma unroll
        for (int kb = 0; kb < 9; kb++){
          const int kk = 9 + kb, tap = kk >> 1;
          short8 a  = *(const short8*)(pb + ((tap/3)*8 + (tap%3))*144 + (kk&1)*64);
          short8 bf = *(const short8*)&wrow[kk*32];
          oacc = __builtin_amdgcn_mfma_f32_16x16x32_bf16(a, bf, oacc, 0, 0, 0);
        }
      }
      int comp = colw*16 + c0;
      if (comp < 18){
        #pragma unroll
        for (int r = 0; r < 4; r++) offsP[kh*288 + (q4 + r)*18 + comp] = oacc[r];
      }
    }
    __syncthreads();

    // C0
    if (tid < 144){
      int p = tp, k = tk;
      int h = srow + (p >> 2), w = scol + (p & 3);
      float oy = offsP[p*18 + 2*k]     + offsP[288 + p*18 + 2*k]     + oby;
      float ox = offsP[p*18 + 2*k + 1] + offsP[288 + p*18 + 2*k + 1] + obx;
      float py = (float)(h + k/3 - 1) + oy;
      float px = (float)(w + k%3 - 1) + ox;
      float y0f = floorf(py), x0f = floorf(px);
      float fy = py - y0f, fx = px - x0f;
      int y0 = (int)y0f, x0 = (int)x0f, y1 = y0 + 1, x1 = x0 + 1;
      bool vy0 = (y0 >= 0) & (y0 < H), vy1 = (y1 >= 0) & (y1 < H);
      bool vx0 = (x0 >= 0) & (x0 < W), vx1 = (x1 >= 0) & (x1 < W);
      int y0c = min(max(y0, 0), H-1), y1c = min(max(y1, 0), H-1);
      int x0c = min(max(x0, 0), W-1), x1c = min(max(x1, 0), W-1);
      float gy = 1.f - fy, gx = 1.f - fx;
      tapW[tid] = make_float4((vy0 & vx0) ? gy*gx : 0.f,
                              (vy0 & vx1) ? gy*fx : 0.f,
                              (vy1 & vx0) ? fy*gx : 0.f,
                              (vy1 & vx1) ? fy*fx : 0.f);
      int ry = y0 - srow + 2, rx = x0 - scol + 2;
      if (((unsigned)ry < 7u) & ((unsigned)rx < 7u)){
        tapIs[tid][0] = (unsigned short)(0x8000u | (ry*8 + rx));
      } else {
        tapIs[tid][0] = (unsigned short)(y0c*W + x0c);
        tapIs[tid][1] = (unsigned short)(y0c*W + x1c);
        tapIs[tid][2] = (unsigned short)(y1c*W + x0c);
        tapIs[tid][3] = (unsigned short)(y1c*W + x1c);
      }
    }
    __syncthreads();

    // C1
    {
      const char* curc8 = (const char*)curu + c0*8;
      int T = wave*36 + quad;
      int p = wave*4, k = quad;
      #pragma unroll
      for (int i = 0; i < 9; i++){
        float4 wv = tapW[T];
        unsigned short t0 = tapIs[T][0];
        uint2 u0, u1, u2, u3;
        if (t0 & 0x8000u){
          const char* pb2 = patchS + (int)(t0 & 0x7fffu)*144 + c0*8;
          u0 = *(const uint2*)(pb2);
          u1 = *(const uint2*)(pb2 + 144);
          u2 = *(const uint2*)(pb2 + 144*8);
          u3 = *(const uint2*)(pb2 + 144*9);
        } else {
          uint2 tw = *(const uint2*)tapIs[T];
          u0 = *(const uint2*)(curc8 + ((size_t)(tw.x & 0xffffu) << 7));
          u1 = *(const uint2*)(curc8 + ((size_t)(tw.x >> 16)     << 7));
          u2 = *(const uint2*)(curc8 + ((size_t)(tw.y & 0xffffu) << 7));
          u3 = *(const uint2*)(curc8 + ((size_t)(tw.y >> 16)     << 7));
        }
        float a0 = wv.x*blo(u0.x) + wv.y*blo(u1.x) + wv.z*blo(u2.x) + wv.w*blo(u3.x);
        float a1 = wv.x*bhi(u0.x) + wv.y*bhi(u1.x) + wv.z*bhi(u2.x) + wv.w*bhi(u3.x);
        float a2 = wv.x*blo(u0.y) + wv.y*blo(u1.y) + wv.z*blo(u2.y) + wv.w*blo(u3.y);
        float a3 = wv.x*bhi(u0.y) + wv.y*bhi(u1.y) + wv.z*bhi(u2.y) + wv.w*bhi(u3.y);
        uint2 pk; pk.x = f2b2(a0, a1); pk.y = f2b2(a2, a3);
        *(uint2*)((char*)&valA[0][0] + p*PITCHB + k*128 + c0*8) = pk;
        T += 4; k += 4; if (k >= 9){ k -= 9; ++p; }
      }
    }
    __syncthreads();

    // D
    f32x4 d0 = {bt2, bt2, bt2, bt2}, d1 = {0,0,0,0};
    #pragma unroll
    for (int kb = 0; kb < 9; kb++){
      short8 a  = *(const short8*)&valA[c0][kb*32 + quad*8];
      short8 bf = *(const short8*)&dcw[n*576 + kb*32 + quad*8];
      d0 = __builtin_amdgcn_mfma_f32_16x16x32_bf16(a, bf, d0, 0, 0, 0);
    }
    #pragma unroll
    for (int kb = 9; kb < 18; kb++){
      short8 a  = *(const short8*)&valA[c0][kb*32 + quad*8];
      short8 bf = *(const short8*)&dcw[n*576 + kb*32 + quad*8];
      d1 = __builtin_amdgcn_mfma_f32_16x16x32_bf16(a, bf, d1, 0, 0, 0);
    }
    f32x4 acc;
    #pragma unroll
    for (int r = 0; r < 4; r++) acc[r] = d0[r] + d1[r];
    float* dcb = dc + ((size_t)b*P + (size_t)(srow + quad)*W + scol)*64;
    #pragma unroll
    for (int r = 0; r < 4; r++) dcb[r*64 + n] = acc[r];
    float s = acc[0] + acc[1] + acc[2] + acc[3];
    s += __shfl_xor(s, 16);
    s += __shfl_xor(s, 32);
    if (quad == 0) atomicAdd(&sums[(LVL*16 + (bid & 15))*256 + (b << 6) + n], s);
  }
}

// ---- phase: deform 4x4 (verbatim R1/R7 body) ----
template<int H, int LVL>
static __device__ void deform_body(char* sm, int bid,
    const unsigned* __restrict__ cur, const float* __restrict__ ws_all,
    const float* __restrict__ off_bias, const float* __restrict__ dc_bias,
    float* __restrict__ dc, float* __restrict__ sums){
  constexpr int W = H, P = H * W;
  constexpr int PITCHB = 584 * 2;
  constexpr int TPR = W/4, TPB = P/16;
  short (*valA)[584] = (short(*)[584])sm;                 // 18688B
  float4* tapW = (float4*)(sm + 18688);                   // 2304B
  unsigned short (*tapIs)[4] = (unsigned short(*)[4])(sm + 20992);  // 1152B
  short* patch = (short*)sm;                              // aliases valA
  float* offsP = (float*)(sm + 8192);
  const short* owt = (const short*)(ws_all + OFF_OWT) + LVL * 32 * 576;
  const short* dcw = (const short*)(ws_all + OFF_DCWT) + (size_t)LVL * 64 * 576;
  const int tid = threadIdx.x;
  const int wave = tid >> 6, lane = tid & 63;
  const int c0 = lane & 15, quad = lane >> 4, q4 = quad * 4;
  const int b = bid / TPB;
  const int rr = bid % TPB;
  const int hrow = (rr / TPR) * 4, wcol = (rr % TPR) * 4;
  const unsigned* curu = cur + (size_t)b * P * 32;
  __syncthreads();                                // LDS reuse fence (vb-loop safe)

  // A
  {
    #pragma unroll
    for (int i = 0; i < 3; i++){
      if (i < 2 || quad == 0){
        int p36 = wave*9 + i*4 + quad;
        int r6 = p36 / 6, c6 = p36 - r6*6;
        int yy = hrow - 1 + r6, xx = wcol - 1 + c6;
        bool v = ((unsigned)yy < (unsigned)H) & ((unsigned)xx < (unsigned)W);
        int idx = v ? (yy*W + xx) : 0;
        uint2 d = *(const uint2*)(curu + (size_t)idx*32 + c0*2);
        if (!v){ d.x = 0u; d.y = 0u; }
        *(uint2*)(patch + p36*72 + c0*4) = d;
      }
    }
  }
  __syncthreads();

  // B
  {
    const int colw = wave & 1, kh = wave >> 1;
    const char* pb = (const char*)patch + ((c0 >> 2) * 6 + (c0 & 3)) * 144 + quad * 16;
    const short* wrow = owt + (colw*16 + c0)*576 + quad*8;
    f32x4 oacc = {0,0,0,0};
    if (kh == 0){
      #pragma unroll
      for (int kb = 0; kb < 9; kb++){
        const int tap = kb >> 1;
        short8 a  = *(const short8*)(pb + ((tap/3)*864 + (tap%3)*144 + (kb&1)*64));
        short8 bf = *(const short8*)&wrow[kb*32];
        oacc = __builtin_amdgcn_mfma_f32_16x16x32_bf16(a, bf, oacc, 0, 0, 0);
      }
    } else {
      #pragma unroll
      for (int kb = 0; kb < 9; kb++){
        const int kk = 9 + kb, tap = kk >> 1;
        short8 a  = *(const short8*)(pb + ((tap/3)*864 + (tap%3)*144 + (kk&1)*64));
        short8 bf = *(const short8*)&wrow[kk*32];
        oacc = __builtin_amdgcn_mfma_f32_16x16x32_bf16(a, bf, oacc, 0, 0, 0);
      }
    }
    int comp = colw*16 + c0;
    if (comp < 18){
      #pragma unroll
      for (int r = 0; r < 4; r++) offsP[kh*288 + (q4 + r)*18 + comp] = oacc[r];
    }
  }
  __syncthreads();

  // C0
  if (tid < 144){
    int p = tid / 9, k = tid % 9;
    int h = hrow + (p >> 2), w = wcol + (p & 3);
    float oy = offsP[p*18 + 2*k]     + offsP[288 + p*18 + 2*k]     + off_bias[LVL*18 + 2*k];
    float ox = offsP[p*18 + 2*k + 1] + offsP[288 + p*18 + 2*k + 1] + off_bias[LVL*18 + 2*k + 1];
    float py = (float)(h + k/3 - 1) + oy;
    float px = (float)(w + k%3 - 1) + ox;
    float y0f = floorf(py), x0f = floorf(px);
    float fy = py - y0f, fx = px - x0f;
    int y0 = (int)y0f, x0 = (int)x0f, y1 = y0 + 1, x1 = x0 + 1;
    bool vy0 = (y0 >= 0) & (y0 < H), vy1 = (y1 >= 0) & (y1 < H);
    bool vx0 = (x0 >= 0) & (x0 < W), vx1 = (x1 >= 0) & (x1 < W);
    int y0c = min(max(y0, 0), H-1), y1c = min(max(y1, 0), H-1);
    int x0c = min(max(x0, 0), W-1), x1c = min(max(x1, 0), W-1);
    float gy = 1.f - fy, gx = 1.f - fx;
    tapW[tid] = make_float4((vy0 & vx0) ? gy*gx : 0.f,
                            (vy0 & vx1) ? gy*fx : 0.f,
                            (vy1 & vx0) ? fy*gx : 0.f,
                            (vy1 & vx1) ? fy*fx : 0.f);
    ushort4v ti = { (unsigned short)(y0c*W + x0c), (unsigned short)(y0c*W + x1c),
                    (unsigned short)(y1c*W + x0c), (unsigned short)(y1c*W + x1c) };
    *(ushort4v*)tapIs[tid] = ti;
  }
  __syncthreads();

  // C1
  {
    const char* curc8 = (const char*)curu + c0*8;
    int T = wave*36 + quad;
    int p = T/9, k = T - p*9;
    #pragma unroll
    for (int i = 0; i < 9; i++){
      float4 wv = tapW[T];
      uint2 tw = *(const uint2*)tapIs[T];
      uint2 u0 = *(const uint2*)(curc8 + ((size_t)(tw.x & 0xffffu) << 7));
      uint2 u1 = *(const uint2*)(curc8 + ((size_t)(tw.x >> 16) << 7));
      uint2 u2 = *(const uint2*)(curc8 + ((size_t)(tw.y & 0xffffu) << 7));
      uint2 u3 = *(const uint2*)(curc8 + ((size_t)(tw.y >> 16) << 7));
      float a0 = wv.x*blo(u0.x) + wv.y*blo(u1.x) + wv.z*blo(u2.x) + wv.w*blo(u3.x);
      float a1 = wv.x*bhi(u0.x) + wv.y*bhi(u1.x) + wv.z*bhi(u2.x) + wv.w*bhi(u3.x);
      float a2 = wv.x*blo(u0.y) + wv.y*blo(u1.y) + wv.z*blo(u2.y) + wv.w*blo(u3.y);
      float a3 = wv.x*bhi(u0.y) + wv.y*bhi(u1.y) + wv.z*bhi(u2.y) + wv.w*bhi(u3.y);
      uint2 pk; pk.x = f2b2(a0, a1); pk.y = f2b2(a2, a3);
      *(uint2*)((char*)&valA[0][0] + p*PITCHB + k*128 + c0*8) = pk;
      T += 4; k += 4; if (k >= 9){ k -= 9; ++p; }
    }
  }
  __syncthreads();

  // D
  const int n = wave*16 + c0;
  float bt2 = dc_bias[LVL*64 + n];
  f32x4 d0 = {bt2, bt2, bt2, bt2}, d1 = {0,0,0,0};
  #pragma unroll
  for (int kb = 0; kb < 9; kb++){
    short8 a  = *(const short8*)&valA[c0][kb*32 + quad*8];
    short8 bf = *(const short8*)&dcw[n*576 + kb*32 + quad*8];
    d0 = __builtin_amdgcn_mfma_f32_16x16x32_bf16(a, bf, d0, 0, 0, 0);
  }
  #pragma unroll
  for (int kb = 9; kb < 18; kb++){
    short8 a  = *(const short8*)&valA[c0][kb*32 + quad*8];
    short8 bf = *(const short8*)&dcw[n*576 + kb*32 + quad*8];
    d1 = __builtin_amdgcn_mfma_f32_16x16x32_bf16(a, bf, d1, 0, 0, 0);
  }
  f32x4 acc;
  #pragma unroll
  for (int r = 0; r < 4; r++) acc[r] = d0[r] + d1[r];
  float* dcb = dc + ((size_t)b*P + (size_t)(hrow + quad)*W + wcol)*64;
  #pragma unroll
  for (int r = 0; r < 4; r++) dcb[r*64 + n] = acc[r];
  float s = acc[0] + acc[1] + acc[2] + acc[3];
  s += __shfl_xor(s, 16);
  s += __shfl_xor(s, 32);
  if (quad == 0) atomicAdd(&sums[(LVL*16 + (bid & 15))*256 + (b << 6) + n], s);
}

// ---- phase: fuse + SE + gate + downsample (verbatim R7 body) ----
template<int W, int LVL>
static __device__ void fuse_body(char* sm, int bid,
    const float* __restrict__ dcv, const float* __restrict__ sums,
    const float* __restrict__ se_w1, const float* __restrict__ se_b1,
    const float* __restrict__ se_w2, const float* __restrict__ se_b2,
    const float* __restrict__ ws_all, float* __restrict__ tmp, unsigned* __restrict__ curn){
  constexpr int P = W * W;
  constexpr bool POOL = (LVL < 3);
  constexpr float invP = 1.f / (float)P;
  float (*fS)[68] = (float(*)[68])sm;             // 17408B
  float* gsh = (float*)(sm + 17408);              // 256B
  const short* wsl = (const short*)(ws_all + OFF_WSUMT) + LVL * 4096;
  const int tid = threadIdx.x, wave = tid >> 6, lane = tid & 63;
  const int c0 = lane & 15, quad = lane >> 4, q4 = quad * 4;
  int b, rp = 0, cs = 0;
  if (POOL){
    constexpr int tilesPerB = P / 64, tilesPerRow = W / 32;
    b = bid / tilesPerB;
    int r = bid % tilesPerB;
    rp = r / tilesPerRow; cs = r % tilesPerRow;
  } else {
    b = (bid * 64) / P;
  }
  __syncthreads();                                // LDS reuse fence (vb-loop safe)

  {
    int sg = tid >> 6, c = tid & 63;
    float part = 0.f;
    #pragma unroll
    for (int s = 0; s < 4; s++) part += sums[(LVL*16 + sg*4 + s)*256 + (b << 6) + c];
    fS[sg][c] = part;
    __syncthreads();
    if (tid < 64){
      int r = tid & 3, j = tid >> 2;
      float hp = 0.f;
      #pragma unroll
      for (int q = 0; q < 4; q++){
        int cq = j*4 + q;
        float m = (fS[0][cq] + fS[1][cq] + fS[2][cq] + fS[3][cq]) * invP;
        hp += m * se_w1[(LVL*4 + r)*64 + cq];
      }
      hp += __shfl_xor(hp, 4);  hp += __shfl_xor(hp, 8);
      hp += __shfl_xor(hp, 16); hp += __shfl_xor(hp, 32);
      float hr = fmaxf(hp + se_b1[LVL*4 + r], 0.f);
      float a = se_b2[LVL*64 + tid];
      #pragma unroll
      for (int r2 = 0; r2 < 4; r2++)
        a += __shfl(hr, r2) * se_w2[(LVL*64 + tid)*4 + r2];
      gsh[tid] = 1.f / (1.f + expf(-a));
    }
    __syncthreads();
  }

  float4 g4 = *(const float4*)&gsh[c0*4];
  #pragma unroll
  for (int i = 0; i < 4; i++){
    int lp = wave*16 + (lane >> 4) + i*4;
    size_t gpix = POOL ? ((size_t)b*P + (size_t)(2*rp + (lp >> 5))*W + cs*32 + (lp & 31))
                       : ((size_t)bid*64 + lp);
    float4 d = *(const float4*)&dcv[gpix*64 + c0*4];
    float4 v = make_float4(d.x*g4.x, d.y*g4.y, d.z*g4.z, d.w*g4.w);
    *(float4*)&fS[lp][c0*4] = v;
  }
  __syncthreads();
  f32x4 acc[4] = {{0,0,0,0},{0,0,0,0},{0,0,0,0},{0,0,0,0}};
  #pragma unroll
  for (int kb = 0; kb < 2; kb++){
    float4 lo = *(const float4*)&fS[wave*16 + c0][kb*32 + quad*8];
    float4 hi = *(const float4*)&fS[wave*16 + c0][kb*32 + quad*8 + 4];
    uint4v ua = {f2b2(lo.x, lo.y), f2b2(lo.z, lo.w), f2b2(hi.x, hi.y), f2b2(hi.z, hi.w)};
    short8 a = __builtin_bit_cast(short8, ua);
    #pragma unroll
    for (int t = 0; t < 4; t++){
      short8 bf = *(const short8*)&wsl[(t*16 + c0)*64 + kb*32 + quad*8];
      acc[t] = __builtin_amdgcn_mfma_f32_16x16x32_bf16(a, bf, acc[t], 0, 0, 0);
    }
  }
  #pragma unroll
  for (int t = 0; t < 4; t++){
    int n = t*16 + c0;
    size_t plane = ((size_t)(b << 6) + n) * P;
    size_t pix = POOL ? ((size_t)(2*rp + (wave >> 1))*W + cs*32 + (wave & 1)*16 + q4)
                      : ((size_t)(bid*64) - (size_t)b*P + wave*16 + q4);
    *(f32x4*)&tmp[plane + pix] = acc[t];
  }
  if constexpr (POOL){
    int j = tid >> 4, uu = tid & 15;
    float4 p0 = *(const float4*)&fS[2*j][uu*4];
    float4 p1 = *(const float4*)&fS[2*j + 1][uu*4];
    float4 p2 = *(const float4*)&fS[32 + 2*j][uu*4];
    float4 p3 = *(const float4*)&fS[33 + 2*j][uu*4];
    float4 av = make_float4(0.25f*(p0.x + p1.x + p2.x + p3.x),
                            0.25f*(p0.y + p1.y + p2.y + p3.y),
                            0.25f*(p0.z + p1.z + p2.z + p3.z),
                            0.25f*(p0.w + p1.w + p2.w + p3.w));
    uint2 pv = make_uint2(f2b2(av.x, av.y), f2b2(av.z, av.w));
    *(uint2*)&curn[((size_t)b*(P/4) + (size_t)rp*(W/2) + cs*16 + j)*32 + uu*2] = pv;
  }
}

// ---- phase: final upsample+sum (grid-strided) ----
static __device__ void final_body(const float* __restrict__ ws_all,
                                  const float* __restrict__ fuse_bias,
                                  float* __restrict__ out, int bid){
  const float* tarr[3] = {ws_all + OFF_T1, ws_all + OFF_T2, ws_all + OFF_T3};
  for (int i = bid*256 + (int)threadIdx.x; i < 4194304; i += GRID*256){
    int w = i & 127, h = (i >> 7) & 127, o = (i >> 14) & 63, b = i >> 20;
    float acc = fuse_bias[o] + ws_all[OFF_T0 + (((size_t)(b << 6) + o) << 14) + (h << 7) + w];
    #pragma unroll
    for (int li = 0; li < 3; li++){
      int l = li + 1, Hl = 128 >> l;
      float scale = 1.0f / (float)(1 << l);
      float sy = fminf(fmaxf((h + 0.5f)*scale - 0.5f, 0.f), (float)(Hl - 1));
      float sx = fminf(fmaxf((w + 0.5f)*scale - 0.5f, 0.f), (float)(Hl - 1));
      int y0 = (int)sy, x0 = (int)sx;
      float fy = sy - y0, fx = sx - x0;
      int y1 = min(y0 + 1, Hl - 1), x1 = min(x0 + 1, Hl - 1);
      const float* tb = tarr[li] + (size_t)((b << 6) + o) * Hl * Hl;
      float v00 = tb[y0*Hl + x0], v01 = tb[y0*Hl + x1];
      float v10 = tb[y1*Hl + x0], v11 = tb[y1*Hl + x1];
      acc += (1.f-fy)*((1.f-fx)*v00 + fx*v01) + fy*((1.f-fx)*v10 + fx*v11);
    }
    out[i] = acc;
  }
}

// ---- whole pipeline as ONE persistent kernel (plain launch, graph-capturable);
//      device-scope atomic barrier replaces kernel boundaries ----
__global__ __launch_bounds__(256, 4) void mega_k(
    const float* __restrict__ x, const float* __restrict__ off_w,
    const float* __restrict__ off_b, const float* __restrict__ dc_w,
    const float* __restrict__ dc_b, const float* __restrict__ se_w1,
    const float* __restrict__ se_b1, const float* __restrict__ se_w2,
    const float* __restrict__ se_b2, const float* __restrict__ fuse_w,
    const float* __restrict__ fuse_b, float* __restrict__ out,
    float* __restrict__ ws){
  __shared__ __align__(16) char sm[SM_BYTES];
  const int bid = blockIdx.x;
  unsigned* cur = (unsigned*)(ws + OFF_CUR);
  unsigned* bar = (unsigned*)(ws + OFF_BAR);
  float* dc = ws + OFF_DC;
  float* sums = ws + OFF_SUMS;

  prep_body(sm, dc_w, off_w, fuse_w, ws, x, cur, bid);
  gbar(bar, 1);
  for (int vb = bid; vb < 1024; vb += GRID)
    deform8_body<128,0>(sm, vb, cur, ws, off_b, dc_b, dc, sums);
  gbar(bar, 2);
  for (int vb = bid; vb < 1024; vb += GRID)
    fuse_body<128,0>(sm, vb, dc, sums, se_w1, se_b1, se_w2, se_b2, ws, ws + OFF_T0, cur);
  gbar(bar, 3);
  for (int vb = bid; vb < 1024; vb += GRID)
    deform_body<64,1>(sm, vb, cur, ws, off_b, dc_b, dc, sums);
  gbar(bar, 4);
  for (int vb = bid; vb < 256; vb += GRID)
    fuse_body<64,1>(sm, vb, dc, sums, se_w1, se_b1, se_w2, se_b2, ws, ws + OFF_T1, cur);
  gbar(bar, 5);
  for (int vb = bid; vb < 256; vb += GRID)
    deform_body<32,2>(sm, vb, cur, ws, off_b, dc_b, dc, sums);
  gbar(bar, 6);
  for (int vb = bid; vb < 64; vb += GRID)
    fuse_body<32,2>(sm, vb, dc, sums, se_w1, se_b1, se_w2, se_b2, ws, ws + OFF_T2, cur);
  gbar(bar, 7);
  for (int vb = bid; vb < 64; vb += GRID)
    deform_body<16,3>(sm, vb, cur, ws, off_b, dc_b, dc, sums);
  gbar(bar, 8);
  for (int vb = bid; vb < 16; vb += GRID)
    fuse_body<16,3>(sm, vb, dc, sums, se_w1, se_b1, se_w2, se_b2, ws, ws + OFF_T3, nullptr);
  gbar(bar, 9);
  final_body(ws, fuse_b, out, bid);
}

extern "C" void kernel_launch(void* const* d_in, const int* in_sizes, int n_in,
                              void* d_out, int out_size, void* d_ws, size_t ws_size,
                              hipStream_t stream){
  (void)in_sizes; (void)n_in; (void)out_size; (void)ws_size;
  const float* x      = (const float*)d_in[0];
  const float* off_w  = (const float*)d_in[1];
  const float* off_b  = (const float*)d_in[2];
  const float* dc_w   = (const float*)d_in[3];
  const float* dc_b   = (const float*)d_in[4];
  const float* se_w1  = (const float*)d_in[5];
  const float* se_b1  = (const float*)d_in[6];
  const float* se_w2  = (const float*)d_in[7];
  const float* se_b2  = (const float*)d_in[8];
  const float* fuse_w = (const float*)d_in[9];
  const float* fuse_b = (const float*)d_in[10];
  float* out = (float*)d_out;
  float* ws = (float*)d_ws;

  // zero the global barrier counter (capture-safe memset node)
  hipMemsetAsync(ws + OFF_BAR, 0, 16, stream);
  mega_k<<<GRID, 256, 0, stream>>>(x, off_w, off_b, dc_w, dc_b,
                                   se_w1, se_b1, se_w2, se_b2,
                                   fuse_w, fuse_b, out, ws);
}

// Round 11
// 218.820 us; speedup vs baseline: 6.2126x; 6.2126x over previous
//
#include <hip/hip_runtime.h>
#include <hip/hip_bf16.h>
#include <math.h>

// All reference tensors are float32 -> inputs are const float*, output float*.

constexpr int Bn = 4;          // batch

typedef __attribute__((ext_vector_type(8))) short short8;   // 8 bf16 (4 VGPRs)
typedef __attribute__((ext_vector_type(4))) float f32x4;    // MFMA 16x16 acc
typedef __attribute__((ext_vector_type(4))) unsigned uint4v;
typedef __attribute__((ext_vector_type(4))) unsigned short ushort4v;

static __device__ __forceinline__ short f2b(float f){
  union { float f; unsigned u; } v; v.f = f;
  unsigned r = v.u + 0x7fffu + ((v.u >> 16) & 1u);   // RNE
  return (short)(r >> 16);
}
// packed f32x2 -> bf16x2 (v_cvt_pk_bf16_f32 on gfx950); low short = x
static __device__ __forceinline__ unsigned f2b2(float x, float y){
  union { __hip_bfloat162 h; unsigned u; } cv;
  cv.h = __float22bfloat162_rn(make_float2(x, y));
  return cv.u;
}
static __device__ __forceinline__ float blo(unsigned u){ return __uint_as_float(u << 16); }
static __device__ __forceinline__ float bhi(unsigned u){ return __uint_as_float(u & 0xffff0000u); }

// ---- workspace layout (float offsets; all multiples of 4 -> 16B aligned) ----
constexpr size_t OFF_CUR   = 0;                         // bf16 [4][16384][64] NHWC
constexpr size_t OFF_DC    = OFF_CUR  + 4194304;        // f32 4*16384*64 NHWC
constexpr size_t OFF_T0    = OFF_DC   + 4194304;        // fuse outputs, CHW [b][o][p], f32
constexpr size_t OFF_T1    = OFF_T0   + 4194304;
constexpr size_t OFF_T2    = OFF_T1   + 1048576;
constexpr size_t OFF_T3    = OFF_T2   + 262144;
constexpr size_t OFF_WSUMT = OFF_T3   + 65536;          // bf16 [4][64][64]   kdim=c
constexpr size_t OFF_DCWT  = OFF_WSUMT + 8192;          // bf16 [4][64][576]  kdim=k*64+c
constexpr size_t OFF_OWT   = OFF_DCWT  + 73728;         // bf16 [4][32][576]  kdim=k*64+c
constexpr size_t OFF_SUMS  = OFF_OWT   + 36864;         // f32 [4][16 slots][256]

// ---- prep+cvt merged: weights -> bf16, cumulative fuse, zero SE sums, and
//      x NCHW f32 -> NHWC bf16 (LDS-tiled transpose). Blocks < 1024 do cvt too. ----
__global__ __launch_bounds__(256) void prepcvt_k(
    const float* __restrict__ dc_w, const float* __restrict__ off_w,
    const float* __restrict__ fuse_w, float* __restrict__ ws,
    const float* __restrict__ x, unsigned* __restrict__ cur){
  __shared__ float t[64][65];
  // prep part (same indexing as prep_k, grid must cover 303104 elements)
  {
    int i = blockIdx.x * 256 + threadIdx.x;
    short* dcwT  = (short*)(ws + OFF_DCWT);
    short* owT   = (short*)(ws + OFF_OWT);
    short* wsumT = (short*)(ws + OFF_WSUMT);
    if (i < 147456){
      int oc = i / 576, r = i % 576, k = r >> 6, c = r & 63;      // oc = l*64+o
      dcwT[i] = f2b(dc_w[(oc*64 + c)*9 + k]);
    } else if (i < 147456 + 73728){
      int tt = i - 147456;
      int lm = tt / 576, l = lm >> 5, m = lm & 31, r = tt % 576, k = r >> 6, c = r & 63;
      owT[tt] = (m < 18) ? f2b(off_w[((l*18 + m)*64 + c)*9 + k]) : (short)0;
    } else if (i < 147456 + 73728 + 16384){
      int tt = i - (147456 + 73728);
      int l = tt / 4096, r = tt % 4096, o = r / 64, c = r % 64;
      float s = 0.f;
      for (int jl = 0; jl <= l; jl++) s += fuse_w[o*256 + jl*64 + c];
      wsumT[tt] = f2b(s);
    } else if (i < 147456 + 73728 + 16384 + 65536){
      ws[OFF_SUMS + (i - (147456 + 73728 + 16384))] = 0.f;
    }
  }
  // cvt part (blocks 0..1023): b(4) x 256 pixel-groups
  if (blockIdx.x < 1024){
    int tile = blockIdx.x;
    int b = tile >> 8, p0 = (tile & 255) << 6;
    int tx = threadIdx.x & 63, ty = threadIdx.x >> 6;
    #pragma unroll
    for (int c = ty; c < 64; c += 4)
      t[c][tx] = x[(((size_t)(b << 6) + c) << 14) + p0 + tx];
    __syncthreads();
    int u = threadIdx.x & 31, pr = threadIdx.x >> 5;   // ch-pair, pixel offset
    #pragma unroll
    for (int i = 0; i < 8; i++){
      int pp = pr + i*8;
      unsigned v = f2b2(t[2*u][pp], t[2*u + 1][pp]);
      cur[((size_t)(b << 14) + p0 + pp)*32 + u] = v;
    }
  }
}

// ---- deform8_k (R7-verified): 8x8 tile / four 4x4 sub-tiles, weights in-loop ----
template<int H, int LVL>
__global__ __launch_bounds__(256, 3) void deform8_k(
    const unsigned* __restrict__ cur, const float* __restrict__ ws_all,
    const float* __restrict__ off_bias, const float* __restrict__ dc_bias,
    float* __restrict__ dc, float* __restrict__ sums){
  constexpr int W = H, P = H * W;
  constexpr int PITCHB = 584 * 2;                 // valA row pitch in bytes (pad 576->584)
  constexpr int TPR8 = W/8, TPB8 = P/64;          // 8x8 tiles per row / per batch
  __shared__ __align__(16) short valA[16][584];   // 18688B; offsP aliases at +8192
  __shared__ __align__(16) char  patchS[64*144];  // 64 px x 128B (pitch 144B) = 9216B
  __shared__ __align__(16) float4 tapW[144];      // bilinear corner weights (per sub-tile)
  __shared__ __align__(8)  unsigned short tapIs[144][4];  // fast: pp|0x8000; slow: 4 idx
  float* offsP = (float*)((char*)&valA[0][0] + 8192);     // [2][16][18] f32 (2304B)
  const short* owt = (const short*)(ws_all + OFF_OWT) + LVL * 32 * 576;
  const short* dcw = (const short*)(ws_all + OFF_DCWT) + (size_t)LVL * 64 * 576;
  const int tid = threadIdx.x;
  const int wave = tid >> 6, lane = tid & 63;
  const int c0 = lane & 15, quad = lane >> 4, q4 = quad * 4;
  const int b = blockIdx.x / TPB8;
  const int rr = blockIdx.x % TPB8;
  const int hrow8 = (rr / TPR8) * 8, wcol8 = (rr % TPR8) * 8;
  const unsigned* curu = cur + (size_t)b * P * 32;
  const int n = wave*16 + c0;
  const float bt2 = dc_bias[LVL*64 + n];
  // per-thread C0 constants
  const int tk = tid % 9, tp = tid / 9;
  float oby = 0.f, obx = 0.f;
  if (tid < 144){
    oby = off_bias[LVL*18 + 2*tk];
    obx = off_bias[LVL*18 + 2*tk + 1];
  }
  const int pl = lane >> 3, cq = lane & 7;        // phase-A roles: pixel-lane, chunk

  #pragma unroll 1
  for (int t = 0; t < 4; t++){
    const int srow = hrow8 + (t >> 1)*4, scol = wcol8 + (t & 1)*4;
    if (t) __syncthreads();                       // patch/valA/tapW reuse fence

    // A: stage 8x8 halo patch (margin +-2), zero-masked; 8 lanes x 16B per pixel
    #pragma unroll
    for (int i = 0; i < 2; i++){
      int pp = wave*16 + i*8 + pl;                // 0..63
      int R = pp >> 3, C = pp & 7;
      int yy = srow - 2 + R, xx = scol - 2 + C;
      bool v = ((unsigned)yy < (unsigned)H) & ((unsigned)xx < (unsigned)W);
      int idx = v ? (yy*W + xx) : 0;
      uint4 d = *(const uint4*)((const char*)curu + (size_t)idx*128 + cq*16);
      if (!v){ d.x = 0; d.y = 0; d.z = 0; d.w = 0; }
      *(uint4*)(patchS + pp*144 + cq*16) = d;
    }
    __syncthreads();

    // B: offset conv [16x576]@[576x32] split over 4 waves (2 col-halves x 2 K-halves)
    {
      const int colw = wave & 1, kh = wave >> 1;
      // lane's tile pixel (tr,tc) = (c0>>2, c0&3) at patch px ((tr+1)*8 + tc+1)
      const char* pb = patchS + (((c0 >> 2) + 1)*8 + (c0 & 3) + 1)*144 + quad*16;
      const short* wrow = owt + (colw*16 + c0)*576 + quad*8;
      f32x4 oacc = {0,0,0,0};
      if (kh == 0){
        #pragma unroll
        for (int kb = 0; kb < 9; kb++){
          const int tap = kb >> 1;
          short8 a  = *(const short8*)(pb + ((tap/3)*8 + (tap%3))*144 + (kb&1)*64);
          short8 bf = *(const short8*)&wrow[kb*32];
          oacc = __builtin_amdgcn_mfma_f32_16x16x32_bf16(a, bf, oacc, 0, 0, 0);
        }
      } else {
        #pragma unroll
        for (int kb = 0; kb < 9; kb++){
          const int kk = 9 + kb, tap = kk >> 1;
          short8 a  = *(const short8*)(pb + ((tap/3)*8 + (tap%3))*144 + (kk&1)*64);
          short8 bf = *(const short8*)&wrow[kk*32];
          oacc = __builtin_amdgcn_mfma_f32_16x16x32_bf16(a, bf, oacc, 0, 0, 0);
        }
      }
      int comp = colw*16 + c0;
      if (comp < 18){
        #pragma unroll
        for (int r = 0; r < 4; r++) offsP[kh*288 + (q4 + r)*18 + comp] = oacc[r];
      }
    }
    __syncthreads();

    // C0: per-tap bilinear weights + corner addressing (LDS fast path if in-patch)
    if (tid < 144){
      int p = tp, k = tk;
      int h = srow + (p >> 2), w = scol + (p & 3);
      float oy = offsP[p*18 + 2*k]     + offsP[288 + p*18 + 2*k]     + oby;
      float ox = offsP[p*18 + 2*k + 1] + offsP[288 + p*18 + 2*k + 1] + obx;
      float py = (float)(h + k/3 - 1) + oy;
      float px = (float)(w + k%3 - 1) + ox;
      float y0f = floorf(py), x0f = floorf(px);
      float fy = py - y0f, fx = px - x0f;
      int y0 = (int)y0f, x0 = (int)x0f, y1 = y0 + 1, x1 = x0 + 1;
      bool vy0 = (y0 >= 0) & (y0 < H), vy1 = (y1 >= 0) & (y1 < H);
      bool vx0 = (x0 >= 0) & (x0 < W), vx1 = (x1 >= 0) & (x1 < W);
      int y0c = min(max(y0, 0), H-1), y1c = min(max(y1, 0), H-1);
      int x0c = min(max(x0, 0), W-1), x1c = min(max(x1, 0), W-1);
      float gy = 1.f - fy, gx = 1.f - fx;
      tapW[tid] = make_float4((vy0 & vx0) ? gy*gx : 0.f,
                              (vy0 & vx1) ? gy*fx : 0.f,
                              (vy1 & vx0) ? fy*gx : 0.f,
                              (vy1 & vx1) ? fy*fx : 0.f);
      int ry = y0 - srow + 2, rx = x0 - scol + 2;      // patch-relative corner00
      if (((unsigned)ry < 7u) & ((unsigned)rx < 7u)){
        tapIs[tid][0] = (unsigned short)(0x8000u | (ry*8 + rx));
      } else {
        tapIs[tid][0] = (unsigned short)(y0c*W + x0c);
        tapIs[tid][1] = (unsigned short)(y0c*W + x1c);
        tapIs[tid][2] = (unsigned short)(y1c*W + x0c);
        tapIs[tid][3] = (unsigned short)(y1c*W + x1c);
      }
    }
    __syncthreads();

    // C1: sample; 16-lane group per tap (4ch each), taps T = wave*36 + quad + 4i
    {
      const char* curc8 = (const char*)curu + c0*8;
      int T = wave*36 + quad;
      int p = wave*4, k = quad;
      #pragma unroll
      for (int i = 0; i < 9; i++){
        float4 wv = tapW[T];
        unsigned short t0 = tapIs[T][0];
        uint2 u0, u1, u2, u3;
        if (t0 & 0x8000u){
          const char* pb2 = patchS + (int)(t0 & 0x7fffu)*144 + c0*8;
          u0 = *(const uint2*)(pb2);
          u1 = *(const uint2*)(pb2 + 144);
          u2 = *(const uint2*)(pb2 + 144*8);
          u3 = *(const uint2*)(pb2 + 144*9);
        } else {
          uint2 tw = *(const uint2*)tapIs[T];
          u0 = *(const uint2*)(curc8 + ((size_t)(tw.x & 0xffffu) << 7));
          u1 = *(const uint2*)(curc8 + ((size_t)(tw.x >> 16)     << 7));
          u2 = *(const uint2*)(curc8 + ((size_t)(tw.y & 0xffffu) << 7));
          u3 = *(const uint2*)(curc8 + ((size_t)(tw.y >> 16)     << 7));
        }
        float a0 = wv.x*blo(u0.x) + wv.y*blo(u1.x) + wv.z*blo(u2.x) + wv.w*blo(u3.x);
        float a1 = wv.x*bhi(u0.x) + wv.y*bhi(u1.x) + wv.z*bhi(u2.x) + wv.w*bhi(u3.x);
        float a2 = wv.x*blo(u0.y) + wv.y*blo(u1.y) + wv.z*blo(u2.y) + wv.w*blo(u3.y);
        float a3 = wv.x*bhi(u0.y) + wv.y*bhi(u1.y) + wv.z*bhi(u2.y) + wv.w*bhi(u3.y);
        uint2 pk; pk.x = f2b2(a0, a1); pk.y = f2b2(a2, a3);
        *(uint2*)((char*)&valA[0][0] + p*PITCHB + k*128 + c0*8) = pk;
        T += 4; k += 4; if (k >= 9){ k -= 9; ++p; }
      }
    }
    __syncthreads();

    // D: deform GEMM [16x576]@[576x64]; weights in-loop from L2; split chain
    f32x4 d0 = {bt2, bt2, bt2, bt2}, d1 = {0,0,0,0};
    #pragma unroll
    for (int kb = 0; kb < 9; kb++){
      short8 a  = *(const short8*)&valA[c0][kb*32 + quad*8];
      short8 bf = *(const short8*)&dcw[n*576 + kb*32 + quad*8];
      d0 = __builtin_amdgcn_mfma_f32_16x16x32_bf16(a, bf, d0, 0, 0, 0);
    }
    #pragma unroll
    for (int kb = 9; kb < 18; kb++){
      short8 a  = *(const short8*)&valA[c0][kb*32 + quad*8];
      short8 bf = *(const short8*)&dcw[n*576 + kb*32 + quad*8];
      d1 = __builtin_amdgcn_mfma_f32_16x16x32_bf16(a, bf, d1, 0, 0, 0);
    }
    f32x4 acc;
    #pragma unroll
    for (int r = 0; r < 4; r++) acc[r] = d0[r] + d1[r];
    // C row q4+r = tile pixel (quad, r) -> global pixel (srow+quad, scol+r)
    float* dcb = dc + ((size_t)b*P + (size_t)(srow + quad)*W + scol)*64;
    #pragma unroll
    for (int r = 0; r < 4; r++) dcb[r*64 + n] = acc[r];
    float s = acc[0] + acc[1] + acc[2] + acc[3];
    s += __shfl_xor(s, 16);
    s += __shfl_xor(s, 32);
    if (quad == 0) atomicAdd(&sums[(LVL*16 + (blockIdx.x & 15))*256 + (b << 6) + n], s);
  }
}

// ---- deform_k (verbatim R1 kernel, PASSED): 4x4 tile, 256 threads ----
// Used for L1-L3 where grid size (1024/256/64) matters more than per-block bytes.
template<int H, int LVL>
__global__ __launch_bounds__(256, 7) void deform_k(
    const unsigned* __restrict__ cur, const float* __restrict__ ws_all,
    const float* __restrict__ off_bias, const float* __restrict__ dc_bias,
    float* __restrict__ dc, float* __restrict__ sums){
  constexpr int W = H, P = H * W;
  constexpr int PITCHB = 584 * 2;                 // valA row pitch in bytes (pad 576->584)
  constexpr int TPR = W/4, TPB = P/16;            // tiles per row / per batch
  __shared__ __align__(16) short valA[16][584];   // 18688B; phases A/B alias patch+offsP here
  __shared__ __align__(16) float4 tapW[144];      // bilinear corner weights
  __shared__ __align__(8)  unsigned short tapIs[144][4];  // corner pixel indices (ushort)
  short* patch = &valA[0][0];                     // [36][72] shorts, 144B rows (5184B)
  float* offsP = (float*)((char*)&valA[0][0] + 8192);     // [2][16][18] f32 (2304B)
  const short* owt = (const short*)(ws_all + OFF_OWT) + LVL * 32 * 576;
  const short* dcw = (const short*)(ws_all + OFF_DCWT) + (size_t)LVL * 64 * 576;
  const int tid = threadIdx.x;
  const int wave = tid >> 6, lane = tid & 63;
  const int c0 = lane & 15, quad = lane >> 4, q4 = quad * 4;
  const int b = blockIdx.x / TPB;
  const int rr = blockIdx.x % TPB;
  const int hrow = (rr / TPR) * 4, wcol = (rr % TPR) * 4;
  const unsigned* curu = cur + (size_t)b * P * 32;

  // A: stage zero-padded 6x6 halo patch (36 px x 128B); 16 lanes x 8B per pixel
  {
    #pragma unroll
    for (int i = 0; i < 3; i++){
      if (i < 2 || quad == 0){
        int p36 = wave*9 + i*4 + quad;            // 0..35
        int r6 = p36 / 6, c6 = p36 - r6*6;
        int yy = hrow - 1 + r6, xx = wcol - 1 + c6;
        bool v = ((unsigned)yy < (unsigned)H) & ((unsigned)xx < (unsigned)W);
        int idx = v ? (yy*W + xx) : 0;
        uint2 d = *(const uint2*)(curu + (size_t)idx*32 + c0*2);
        if (!v){ d.x = 0u; d.y = 0u; }
        *(uint2*)(patch + p36*72 + c0*4) = d;
      }
    }
  }
  __syncthreads();

  // B: offset conv [16x576]@[576x32] split over 4 waves (2 col-halves x 2 K-halves);
  //    A-fragments read from patch via compile-time stencil offsets off one row base.
  {
    const int colw = wave & 1, kh = wave >> 1;
    const char* pb = (const char*)patch + ((c0 >> 2) * 6 + (c0 & 3)) * 144 + quad * 16;
    const short* wrow = owt + (colw*16 + c0)*576 + quad*8;
    f32x4 oacc = {0,0,0,0};
    if (kh == 0){
      #pragma unroll
      for (int kb = 0; kb < 9; kb++){
        const int tap = kb >> 1;
        short8 a  = *(const short8*)(pb + ((tap/3)*864 + (tap%3)*144 + (kb&1)*64));
        short8 bf = *(const short8*)&wrow[kb*32];
        oacc = __builtin_amdgcn_mfma_f32_16x16x32_bf16(a, bf, oacc, 0, 0, 0);
      }
    } else {
      #pragma unroll
      for (int kb = 0; kb < 9; kb++){
        const int kk = 9 + kb, tap = kk >> 1;
        short8 a  = *(const short8*)(pb + ((tap/3)*864 + (tap%3)*144 + (kk&1)*64));
        short8 bf = *(const short8*)&wrow[kk*32];
        oacc = __builtin_amdgcn_mfma_f32_16x16x32_bf16(a, bf, oacc, 0, 0, 0);
      }
    }
    int comp = colw*16 + c0;
    if (comp < 18){
      #pragma unroll
      for (int r = 0; r < 4; r++) offsP[kh*288 + (q4 + r)*18 + comp] = oacc[r];
    }
  }
  __syncthreads();

  // C0: per-tap bilinear weights + corner pixel indices
  if (tid < 144){
    int p = tid / 9, k = tid % 9;
    int h = hrow + (p >> 2), w = wcol + (p & 3);
    float oy = offsP[p*18 + 2*k]     + offsP[288 + p*18 + 2*k]     + off_bias[LVL*18 + 2*k];
    float ox = offsP[p*18 + 2*k + 1] + offsP[288 + p*18 + 2*k + 1] + off_bias[LVL*18 + 2*k + 1];
    float py = (float)(h + k/3 - 1) + oy;
    float px = (float)(w + k%3 - 1) + ox;
    float y0f = floorf(py), x0f = floorf(px);
    float fy = py - y0f, fx = px - x0f;
    int y0 = (int)y0f, x0 = (int)x0f, y1 = y0 + 1, x1 = x0 + 1;
    bool vy0 = (y0 >= 0) & (y0 < H), vy1 = (y1 >= 0) & (y1 < H);
    bool vx0 = (x0 >= 0) & (x0 < W), vx1 = (x1 >= 0) & (x1 < W);
    int y0c = min(max(y0, 0), H-1), y1c = min(max(y1, 0), H-1);
    int x0c = min(max(x0, 0), W-1), x1c = min(max(x1, 0), W-1);
    float gy = 1.f - fy, gx = 1.f - fx;
    tapW[tid] = make_float4((vy0 & vx0) ? gy*gx : 0.f,
                            (vy0 & vx1) ? gy*fx : 0.f,
                            (vy1 & vx0) ? fy*gx : 0.f,
                            (vy1 & vx1) ? fy*fx : 0.f);
    ushort4v ti = { (unsigned short)(y0c*W + x0c), (unsigned short)(y0c*W + x1c),
                    (unsigned short)(y1c*W + x0c), (unsigned short)(y1c*W + x1c) };
    *(ushort4v*)tapIs[tid] = ti;
  }
  __syncthreads();

  // C1: sample from bf16 cur; 4 taps/wave-iter (16 lanes x uint2 = 4ch each), 9 iters
  {
    const char* curc8 = (const char*)curu + c0*8;
    int T = wave*36 + quad;
    int p = T/9, k = T - p*9;
    #pragma unroll
    for (int i = 0; i < 9; i++){
      float4 wv = tapW[T];
      uint2 tw = *(const uint2*)tapIs[T];
      uint2 u0 = *(const uint2*)(curc8 + ((size_t)(tw.x & 0xffffu) << 7));
      uint2 u1 = *(const uint2*)(curc8 + ((size_t)(tw.x >> 16) << 7));
      uint2 u2 = *(const uint2*)(curc8 + ((size_t)(tw.y & 0xffffu) << 7));
      uint2 u3 = *(const uint2*)(curc8 + ((size_t)(tw.y >> 16) << 7));
      float a0 = wv.x*blo(u0.x) + wv.y*blo(u1.x) + wv.z*blo(u2.x) + wv.w*blo(u3.x);
      float a1 = wv.x*bhi(u0.x) + wv.y*bhi(u1.x) + wv.z*bhi(u2.x) + wv.w*bhi(u3.x);
      float a2 = wv.x*blo(u0.y) + wv.y*blo(u1.y) + wv.z*blo(u2.y) + wv.w*blo(u3.y);
      float a3 = wv.x*bhi(u0.y) + wv.y*bhi(u1.y) + wv.z*bhi(u2.y) + wv.w*bhi(u3.y);
      uint2 pk; pk.x = f2b2(a0, a1); pk.y = f2b2(a2, a3);
      *(uint2*)((char*)&valA[0][0] + p*PITCHB + k*128 + c0*8) = pk;
      T += 4; k += 4; if (k >= 9){ k -= 9; ++p; }
    }
  }
  __syncthreads();

  // D: deform GEMM [16x576]@[576x64]; wave w takes cols 16w..16w+15; split chain
  const int n = wave*16 + c0;
  float bt2 = dc_bias[LVL*64 + n];
  f32x4 d0 = {bt2, bt2, bt2, bt2}, d1 = {0,0,0,0};
  #pragma unroll
  for (int kb = 0; kb < 9; kb++){
    short8 a  = *(const short8*)&valA[c0][kb*32 + quad*8];
    short8 bf = *(const short8*)&dcw[n*576 + kb*32 + quad*8];
    d0 = __builtin_amdgcn_mfma_f32_16x16x32_bf16(a, bf, d0, 0, 0, 0);
  }
  #pragma unroll
  for (int kb = 9; kb < 18; kb++){
    short8 a  = *(const short8*)&valA[c0][kb*32 + quad*8];
    short8 bf = *(const short8*)&dcw[n*576 + kb*32 + quad*8];
    d1 = __builtin_amdgcn_mfma_f32_16x16x32_bf16(a, bf, d1, 0, 0, 0);
  }
  f32x4 acc;
  #pragma unroll
  for (int r = 0; r < 4; r++) acc[r] = d0[r] + d1[r];
  // C row q4+r = tile pixel (quad, r) -> global pixel (hrow+quad, wcol+r)
  float* dcb = dc + ((size_t)b*P + (size_t)(hrow + quad)*W + wcol)*64;
  #pragma unroll
  for (int r = 0; r < 4; r++) dcb[r*64 + n] = acc[r];
  float s = acc[0] + acc[1] + acc[2] + acc[3];
  s += __shfl_xor(s, 16);
  s += __shfl_xor(s, 32);
  if (quad == 0) atomicAdd(&sums[(LVL*16 + (blockIdx.x & 15))*256 + (b << 6) + n], s);
}

// ---- fuse + SE gates + gate + downsample: gates from sums (per block), then
//      (dc*g) @ Wsum_l -> tmp_l (CHW f32); 2x2 avg pool of gated vals -> bf16 cur_{l+1} ----
template<int W, int LVL>
__global__ __launch_bounds__(256) void fuse_gd_k(
    const float* __restrict__ dcv, const float* __restrict__ sums,
    const float* __restrict__ se_w1, const float* __restrict__ se_b1,
    const float* __restrict__ se_w2, const float* __restrict__ se_b2,
    const float* __restrict__ ws_all, float* __restrict__ tmp, unsigned* __restrict__ curn){
  constexpr int P = W * W;
  constexpr bool POOL = (LVL < 3);
  constexpr float invP = 1.f / (float)P;
  __shared__ __align__(16) float fS[64][68];      // gated fp32 values, pad 64->68
  __shared__ __align__(16) float gsh[64];
  const short* wsl = (const short*)(ws_all + OFF_WSUMT) + LVL * 4096;
  const int tid = threadIdx.x, wave = tid >> 6, lane = tid & 63;
  const int c0 = lane & 15, quad = lane >> 4, q4 = quad * 4;
  int b, rp = 0, cs = 0;
  if (POOL){
    constexpr int tilesPerB = P / 64, tilesPerRow = W / 32;
    b = blockIdx.x / tilesPerB;
    int r = blockIdx.x % tilesPerB;
    rp = r / tilesPerRow; cs = r % tilesPerRow;
  } else {
    b = (blockIdx.x * 64) / P;
  }

  // SE gates (redundant per block): slot partials -> mean -> fc-relu-fc-sigmoid
  {
    int sg = tid >> 6, c = tid & 63;
    float part = 0.f;
    #pragma unroll
    for (int s = 0; s < 4; s++) part += sums[(LVL*16 + sg*4 + s)*256 + (b << 6) + c];
    fS[sg][c] = part;
    __syncthreads();
    if (tid < 64){
      int r = tid & 3, j = tid >> 2;
      float hp = 0.f;
      #pragma unroll
      for (int q = 0; q < 4; q++){
        int cq = j*4 + q;
        float m = (fS[0][cq] + fS[1][cq] + fS[2][cq] + fS[3][cq]) * invP;
        hp += m * se_w1[(LVL*4 + r)*64 + cq];
      }
      hp += __shfl_xor(hp, 4);  hp += __shfl_xor(hp, 8);
      hp += __shfl_xor(hp, 16); hp += __shfl_xor(hp, 32);
      float hr = fmaxf(hp + se_b1[LVL*4 + r], 0.f);
      float a = se_b2[LVL*64 + tid];
      #pragma unroll
      for (int r2 = 0; r2 < 4; r2++)
        a += __shfl(hr, r2) * se_w2[(LVL*64 + tid)*4 + r2];
      gsh[tid] = 1.f / (1.f + expf(-a));
    }
    __syncthreads();
  }

  // stage gated fp32 values
  float4 g4 = *(const float4*)&gsh[c0*4];
  #pragma unroll
  for (int i = 0; i < 4; i++){
    int lp = wave*16 + (lane >> 4) + i*4;
    size_t gpix = POOL ? ((size_t)b*P + (size_t)(2*rp + (lp >> 5))*W + cs*32 + (lp & 31))
                       : ((size_t)blockIdx.x*64 + lp);
    float4 d = *(const float4*)&dcv[gpix*64 + c0*4];
    float4 v = make_float4(d.x*g4.x, d.y*g4.y, d.z*g4.z, d.w*g4.w);
    *(float4*)&fS[lp][c0*4] = v;
  }
  __syncthreads();
  // fuse MFMA [16x64]@[64x64] per wave
  f32x4 acc[4] = {{0,0,0,0},{0,0,0,0},{0,0,0,0},{0,0,0,0}};
  #pragma unroll
  for (int kb = 0; kb < 2; kb++){
    float4 lo = *(const float4*)&fS[wave*16 + c0][kb*32 + quad*8];
    float4 hi = *(const float4*)&fS[wave*16 + c0][kb*32 + quad*8 + 4];
    uint4v ua = {f2b2(lo.x, lo.y), f2b2(lo.z, lo.w), f2b2(hi.x, hi.y), f2b2(hi.z, hi.w)};
    short8 a = __builtin_bit_cast(short8, ua);
    #pragma unroll
    for (int t = 0; t < 4; t++){
      short8 bf = *(const short8*)&wsl[(t*16 + c0)*64 + kb*32 + quad*8];
      acc[t] = __builtin_amdgcn_mfma_f32_16x16x32_bf16(a, bf, acc[t], 0, 0, 0);
    }
  }
  #pragma unroll
  for (int t = 0; t < 4; t++){
    int n = t*16 + c0;
    size_t plane = ((size_t)(b << 6) + n) * P;
    size_t pix = POOL ? ((size_t)(2*rp + (wave >> 1))*W + cs*32 + (wave & 1)*16 + q4)
                      : ((size_t)(blockIdx.x*64) - (size_t)b*P + wave*16 + q4);
    *(f32x4*)&tmp[plane + pix] = acc[t];
  }
  // 2x2 avg pool of gated values -> next level input (bf16 NHWC)
  if constexpr (POOL){
    int j = tid >> 4, uu = tid & 15;
    float4 p0 = *(const float4*)&fS[2*j][uu*4];
    float4 p1 = *(const float4*)&fS[2*j + 1][uu*4];
    float4 p2 = *(const float4*)&fS[32 + 2*j][uu*4];
    float4 p3 = *(const float4*)&fS[33 + 2*j][uu*4];
    float4 av = make_float4(0.25f*(p0.x + p1.x + p2.x + p3.x),
                            0.25f*(p0.y + p1.y + p2.y + p3.y),
                            0.25f*(p0.z + p1.z + p2.z + p3.z),
                            0.25f*(p0.w + p1.w + p2.w + p3.w));
    uint2 pv = make_uint2(f2b2(av.x, av.y), f2b2(av.z, av.w));
    *(uint2*)&curn[((size_t)b*(P/4) + (size_t)rp*(W/2) + cs*16 + j)*32 + uu*2] = pv;
  }
}

// ---- final: 4x bilinear upsample (CHW planes) + sum + fuse bias -> f32 NCHW ----
// v11: 4 consecutive-w pixels per thread (shares o,h,b and per-level y0/y1/fy),
//      float4 T0 read + float4 out store; grid 16384 -> 4096.
__global__ __launch_bounds__(256) void final_k(const float* __restrict__ ws_all,
                                               const float* __restrict__ fuse_bias,
                                               float* __restrict__ out){
  int i4 = (blockIdx.x * 256 + threadIdx.x) << 2;
  int w = i4 & 127, h = (i4 >> 7) & 127, o = (i4 >> 14) & 63, b = i4 >> 20;
  float fb = fuse_bias[o];
  float4 t0 = *(const float4*)&ws_all[OFF_T0 + (((size_t)(b << 6) + o) << 14) + (h << 7) + w];
  float acc[4] = {fb + t0.x, fb + t0.y, fb + t0.z, fb + t0.w};
  const float* tarr[3] = {ws_all + OFF_T1, ws_all + OFF_T2, ws_all + OFF_T3};
  #pragma unroll
  for (int li = 0; li < 3; li++){
    int l = li + 1, Hl = 128 >> l;
    float scale = 1.0f / (float)(1 << l);
    float sy = fminf(fmaxf((h + 0.5f)*scale - 0.5f, 0.f), (float)(Hl - 1));
    int y0 = (int)sy;
    float fy = sy - y0;
    int y1 = min(y0 + 1, Hl - 1);
    const float* tb = tarr[li] + (size_t)((b << 6) + o) * Hl * Hl;
    const float* r0 = tb + y0*Hl;
    const float* r1 = tb + y1*Hl;
    #pragma unroll
    for (int j = 0; j < 4; j++){
      float sx = fminf(fmaxf((w + j + 0.5f)*scale - 0.5f, 0.f), (float)(Hl - 1));
      int x0 = (int)sx;
      float fx = sx - x0;
      int x1 = min(x0 + 1, Hl - 1);
      float v00 = r0[x0], v01 = r0[x1];
      float v10 = r1[x0], v11 = r1[x1];
      acc[j] += (1.f-fy)*((1.f-fx)*v00 + fx*v01) + fy*((1.f-fx)*v10 + fx*v11);
    }
  }
  *(float4*)&out[i4] = make_float4(acc[0], acc[1], acc[2], acc[3]);
}

extern "C" void kernel_launch(void* const* d_in, const int* in_sizes, int n_in,
                              void* d_out, int out_size, void* d_ws, size_t ws_size,
                              hipStream_t stream){
  (void)in_sizes; (void)n_in; (void)out_size; (void)ws_size;
  const float* x      = (const float*)d_in[0];
  const float* off_w  = (const float*)d_in[1];
  const float* off_b  = (const float*)d_in[2];
  const float* dc_w   = (const float*)d_in[3];
  const float* dc_b   = (const float*)d_in[4];
  const float* se_w1  = (const float*)d_in[5];
  const float* se_b1  = (const float*)d_in[6];
  const float* se_w2  = (const float*)d_in[7];
  const float* se_b2  = (const float*)d_in[8];
  const float* fuse_w = (const float*)d_in[9];
  const float* fuse_b = (const float*)d_in[10];
  float* out = (float*)d_out;
  float* ws = (float*)d_ws;
  unsigned* cur = (unsigned*)(ws + OFF_CUR);   // bf16 NHWC, 2ch per uint
  float* dc   = ws + OFF_DC;
  float* tmp[4] = {ws + OFF_T0, ws + OFF_T1, ws + OFF_T2, ws + OFF_T3};
  float* sums = ws + OFF_SUMS;

  // merged prep + cvt (prep needs 1184 blocks; cvt uses the first 1024)
  prepcvt_k<<<(303104 + 255)/256, 256, 0, stream>>>(dc_w, off_w, fuse_w, ws, x, cur);

  // L0: 8x8-tile variant (R7-verified)
  deform8_k<128,0><<<1024, 256, 0, stream>>>(cur, ws, off_b, dc_b, dc, sums);
  fuse_gd_k<128,0><<<1024, 256, 0, stream>>>(dc, sums, se_w1, se_b1, se_w2, se_b2, ws, tmp[0], cur);
  // L1-L3: 4x4-tile variant (R1-verified; keeps grids 1024/256/64)
  deform_k<64,1><<<1024, 256, 0, stream>>>(cur, ws, off_b, dc_b, dc, sums);
  fuse_gd_k<64,1><<<256, 256, 0, stream>>>(dc, sums, se_w1, se_b1, se_w2, se_b2, ws, tmp[1], cur);
  deform_k<32,2><<<256, 256, 0, stream>>>(cur, ws, off_b, dc_b, dc, sums);
  fuse_gd_k<32,2><<<64, 256, 0, stream>>>(dc, sums, se_w1, se_b1, se_w2, se_b2, ws, tmp[2], cur);
  deform_k<16,3><<<64, 256, 0, stream>>>(cur, ws, off_b, dc_b, dc, sums);
  fuse_gd_k<16,3><<<16, 256, 0, stream>>>(dc, sums, se_w1, se_b1, se_w2, se_b2, ws, tmp[3], nullptr);

  final_k<<<4096, 256, 0, stream>>>(ws, fuse_b, out);
}